// Round 12
// baseline (351.133 us; speedup 1.0000x reference)
//
#include <hip/hip_runtime.h>
#include <hip/hip_bf16.h>

#define TSTEPS 256
#define NF 5
#define BT 8            // batches per block (sparse rows 4g+0,4g+1 <-> batch 2g+b)
#define NBLK 512        // 128-thread blocks -> 2 blocks/CU -> 1 wave/SIMD
#define LDH0 72         // h row stride in ushorts (144B, b128-aligned)
#define SLOT (16 * LDH0)

typedef __attribute__((ext_vector_type(8))) short bf16x8;
typedef __attribute__((ext_vector_type(4))) float f32x4;

#define LOG2E 1.4426950408889634f
#define TWOLOG2E 2.8853900817779268f

__device__ __forceinline__ ushort f2bf(float f) {
    union { float f; unsigned u; } v; v.f = f;
    unsigned u = v.u;
    unsigned r = (u + 0x7FFFu + ((u >> 16) & 1u)) >> 16;  // RNE
    return (ushort)r;
}
__device__ __forceinline__ float bf2f(ushort s) {
    union { unsigned u; float f; } v; v.u = ((unsigned)s) << 16;
    return v.f;
}
__device__ __forceinline__ unsigned pk_bf16(float lo, float hi) {
    unsigned pk;
    asm("v_cvt_pk_bf16_f32 %0, %1, %2" : "=v"(pk) : "v"(lo), "v"(hi));
    return pk;
}
// fused LSTM cell: preacts pre-scaled (i,f,o: +log2e; g: +2log2e). 5 exp2 + 2 rcp.
__device__ __forceinline__ float cellfuse(float xi, float xf, float xg, float xo, float& cst) {
    float ei = __builtin_amdgcn_exp2f(xi);
    float ef = __builtin_amdgcn_exp2f(xf);
    float Eg = __builtin_amdgcn_exp2f(xg);
    float eo = __builtin_amdgcn_exp2f(xo);
    float a1 = ei + 1.0f, a2 = ef + 1.0f, a3 = Eg + 1.0f, a4 = Eg - 1.0f;
    float P  = a1 * a3;
    float t1 = ef * cst;
    float t3 = (a2 * ei) * a4;
    float num = fmaf(t1, P, t3);
    float R  = __builtin_amdgcn_rcpf(P * a2);
    float cn = num * R;
    cst = cn;
    float ct = __builtin_amdgcn_fmed3f(cn * TWOLOG2E, -15.0f, 15.0f);
    float Ec = __builtin_amdgcn_exp2f(ct);
    return (eo * (Ec - 1.0f)) * __builtin_amdgcn_rcpf((eo + 1.0f) * (Ec + 1.0f));
}

__global__ __launch_bounds__(128, 1)
void lstm2_kernel(const float* __restrict__ x,
                  const float* __restrict__ Wih0, const float* __restrict__ Whh0,
                  const float* __restrict__ bih0, const float* __restrict__ bhh0,
                  const float* __restrict__ Wih1, const float* __restrict__ Whh1,
                  const float* __restrict__ bih1, const float* __restrict__ bhh1,
                  const float* __restrict__ Wfc, const float* __restrict__ bfc,
                  float* __restrict__ out)
{
    __shared__ ushort xs[TSTEPS * BT * 8];   // bf16 x [t][b][8]; cols 5,6=1.0 (bias), 7=0
    __shared__ ushort hb[5 * SLOT];          // slots 0..3 = h0 ring; slot 4 = h1
    __shared__ int    flags[2];              // [0]=wave0 steps done, [1]=wave1 steps done

    const int tid = threadIdx.x;
    const int w   = tid >> 6;    // wave 0: layer0 producer; wave 1: layer1 consumer
    const int l   = tid & 63;
    const int g   = l >> 4;      // k-group / D-row group
    const int lr  = l & 15;      // A row / B,D col within tile
    const int bb  = blockIdx.x * BT;

    if (tid < 2) flags[tid] = 0;

    // ---- stage x as bf16 [t][b][8], cols 5,6 = 1.0 for the L0 bias trick ----
    {
        const int b  = tid & 7;
        const int t0 = tid >> 3;
        const ushort one = f2bf(1.0f);
        for (int tt = t0; tt < TSTEPS; tt += 16) {
            const float* xp = x + ((size_t)(bb + b) * TSTEPS + tt) * NF;
            bf16x8 v;
            v[0] = (short)f2bf(xp[0]); v[1] = (short)f2bf(xp[1]);
            v[2] = (short)f2bf(xp[2]); v[3] = (short)f2bf(xp[3]);
            v[4] = (short)f2bf(xp[4]); v[5] = (short)one; v[6] = (short)one; v[7] = 0;
            *(bf16x8*)&xs[(tt * BT + b) * 8] = v;
        }
    }
    for (int i = tid; i < 5 * SLOT; i += 128) hb[i] = 0;

    __syncthreads();   // x staged, buffers zeroed, flags zeroed

    const int arow  = lr * LDH0;
    const int wrow0 = (4 * g + 0) * LDH0 + lr;
    const int wrow1 = (4 * g + 1) * LDH0 + lr;
    const f32x4 kZ = {0, 0, 0, 0};
    const bf16x8 kZ8 = {0, 0, 0, 0, 0, 0, 0, 0};
    volatile int* vf = flags;
    float h1f[8] = {0, 0, 0, 0, 0, 0, 0, 0};

    if (w == 0) {
        // ================= WAVE 0: layer 0, all 64 units, 8 batches =================
        // tile idx ti = gate*4 + ub; col n = gate*64 + ub*16 + lr
        bf16x8 w0h[16][2], w0x[16];
        #pragma unroll
        for (int gate = 0; gate < 4; ++gate) {
            const float sc = (gate == 2) ? TWOLOG2E : LOG2E;
            #pragma unroll
            for (int ub = 0; ub < 4; ++ub) {
                const int n = gate * 64 + ub * 16 + lr;
                const int ti = gate * 4 + ub;
                #pragma unroll
                for (int c = 0; c < 2; ++c) {
                    const float* p = Whh0 + n * 64 + 32 * c + 8 * g;
                    bf16x8 v;
                    #pragma unroll
                    for (int j = 0; j < 8; ++j) v[j] = (short)f2bf(p[j] * sc);
                    w0h[ti][c] = v;
                }
                const float b0 = (bih0[n] + bhh0[n]) * sc;
                const ushort bhi = f2bf(b0);
                const ushort blo = f2bf(b0 - bf2f(bhi));
                bf16x8 v;
                #pragma unroll
                for (int j = 0; j < 8; ++j) {
                    int kk = 8 * g + j;
                    ushort val = 0;
                    if (kk < NF) val = f2bf(Wih0[n * NF + kk] * sc);
                    else if (kk == 5) val = bhi;
                    else if (kk == 6) val = blo;
                    v[j] = (short)val;
                }
                w0x[ti] = v;
            }
        }
        float c0[8] = {0, 0, 0, 0, 0, 0, 0, 0};
        const bool xlane = (g == 0) && ((lr & 2) == 0);
        const int  bx    = 2 * (lr >> 2) + (lr & 1);

        auto step0 = [&](int t, int rs, int ws) {
            while (vf[1] + 3 < t) {}            // ring backpressure (depth 4)
            asm volatile("" ::: "memory");
            const ushort* rb = &hb[rs * SLOT];
            bf16x8 a0 = *(const bf16x8*)&rb[arow + 8 * g];
            bf16x8 a1 = *(const bf16x8*)&rb[arow + 32 + 8 * g];
            bf16x8 axv = *(const bf16x8*)&xs[(t * BT + bx) * 8];
            bf16x8 ax = xlane ? axv : kZ8;
            f32x4 acc[16];
            #pragma unroll
            for (int i = 0; i < 16; ++i) acc[i] = __builtin_amdgcn_mfma_f32_16x16x32_bf16(a0, w0h[i][0], kZ, 0, 0, 0);
            #pragma unroll
            for (int i = 0; i < 16; ++i) acc[i] = __builtin_amdgcn_mfma_f32_16x16x32_bf16(a1, w0h[i][1], acc[i], 0, 0, 0);
            #pragma unroll
            for (int i = 0; i < 16; ++i) acc[i] = __builtin_amdgcn_mfma_f32_16x16x32_bf16(ax, w0x[i], acc[i], 0, 0, 0);
            ushort* wb = &hb[ws * SLOT];
            #pragma unroll
            for (int ub = 0; ub < 4; ++ub) {
                float ha  = cellfuse(acc[ub][0], acc[4 + ub][0], acc[8 + ub][0], acc[12 + ub][0], c0[2 * ub + 0]);
                float hbv = cellfuse(acc[ub][1], acc[4 + ub][1], acc[8 + ub][1], acc[12 + ub][1], c0[2 * ub + 1]);
                unsigned pk = pk_bf16(ha, hbv);
                wb[wrow0 + ub * 16] = (ushort)pk;
                wb[wrow1 + ub * 16] = (ushort)(pk >> 16);
            }
            asm volatile("s_waitcnt lgkmcnt(0)" ::: "memory");
            if (l == 0) vf[0] = t + 1;          // publish h0(t)
        };
        #pragma unroll 1
        for (int t = 0; t < TSTEPS; t += 4) {
            step0(t + 0, 3, 0);
            step0(t + 1, 0, 1);
            step0(t + 2, 1, 2);
            step0(t + 3, 2, 3);
        }
    } else {
        // ================= WAVE 1: layer 1, all 64 units, 8 batches =================
        bf16x8 w1[16][4];
        float  b1v[16];
        #pragma unroll
        for (int gate = 0; gate < 4; ++gate) {
            const float sc = (gate == 2) ? TWOLOG2E : LOG2E;
            #pragma unroll
            for (int ub = 0; ub < 4; ++ub) {
                const int n = gate * 64 + ub * 16 + lr;
                const int ti = gate * 4 + ub;
                b1v[ti] = (bih1[n] + bhh1[n]) * sc;
                #pragma unroll
                for (int c = 0; c < 4; ++c) {
                    const float* p = (c < 2) ? (Wih1 + n * 64 + 32 * c + 8 * g)
                                             : (Whh1 + n * 64 + 32 * (c - 2) + 8 * g);
                    bf16x8 v;
                    #pragma unroll
                    for (int j = 0; j < 8; ++j) v[j] = (short)f2bf(p[j] * sc);
                    w1[ti][c] = v;
                }
            }
        }
        float c1[8] = {0, 0, 0, 0, 0, 0, 0, 0};
        ushort* hb1 = &hb[4 * SLOT];

        auto step1 = [&](int s, int rs) {
            while (vf[0] < s + 1) {}            // wait for h0(s)
            asm volatile("" ::: "memory");
            const ushort* rb = &hb[rs * SLOT];
            bf16x8 a0 = *(const bf16x8*)&rb[arow + 8 * g];
            bf16x8 a1 = *(const bf16x8*)&rb[arow + 32 + 8 * g];
            bf16x8 a2 = *(const bf16x8*)&hb1[arow + 8 * g];        // h1(s-1), own
            bf16x8 a3 = *(const bf16x8*)&hb1[arow + 32 + 8 * g];
            f32x4 acc[16];
            #pragma unroll
            for (int i = 0; i < 16; ++i) acc[i] = __builtin_amdgcn_mfma_f32_16x16x32_bf16(a0, w1[i][0], kZ, 0, 0, 0);
            #pragma unroll
            for (int i = 0; i < 16; ++i) acc[i] = __builtin_amdgcn_mfma_f32_16x16x32_bf16(a1, w1[i][1], acc[i], 0, 0, 0);
            #pragma unroll
            for (int i = 0; i < 16; ++i) acc[i] = __builtin_amdgcn_mfma_f32_16x16x32_bf16(a2, w1[i][2], acc[i], 0, 0, 0);
            #pragma unroll
            for (int i = 0; i < 16; ++i) acc[i] = __builtin_amdgcn_mfma_f32_16x16x32_bf16(a3, w1[i][3], acc[i], 0, 0, 0);
            #pragma unroll
            for (int ub = 0; ub < 4; ++ub) {
                float ha  = cellfuse(acc[ub][0] + b1v[ub],          acc[4 + ub][0] + b1v[4 + ub],
                                     acc[8 + ub][0] + b1v[8 + ub],  acc[12 + ub][0] + b1v[12 + ub], c1[2 * ub + 0]);
                float hbv = cellfuse(acc[ub][1] + b1v[ub],          acc[4 + ub][1] + b1v[4 + ub],
                                     acc[8 + ub][1] + b1v[8 + ub],  acc[12 + ub][1] + b1v[12 + ub], c1[2 * ub + 1]);
                h1f[2 * ub + 0] = ha;
                h1f[2 * ub + 1] = hbv;
                unsigned pk = pk_bf16(ha, hbv);
                hb1[wrow0 + ub * 16] = (ushort)pk;
                hb1[wrow1 + ub * 16] = (ushort)(pk >> 16);
            }
            asm volatile("s_waitcnt lgkmcnt(0)" ::: "memory");
            if (l == 0) vf[1] = s + 1;          // slot rs consumed; h1(s) done
        };
        #pragma unroll 1
        for (int s = 0; s < TSTEPS; s += 4) {
            step1(s + 0, 0);
            step1(s + 1, 1);
            step1(s + 2, 2);
            step1(s + 3, 3);
        }
    }

    __syncthreads();   // both waves finished; xs now dead
    float* hfin = (float*)xs;
    if (w == 1) {
        #pragma unroll
        for (int ub = 0; ub < 4; ++ub) {
            hfin[(2 * g + 0) * 64 + ub * 16 + lr] = h1f[2 * ub + 0];
            hfin[(2 * g + 1) * 64 + ub * 16 + lr] = h1f[2 * ub + 1];
        }
    }
    __syncthreads();
    if (tid < BT * 2) {
        const int b = tid >> 1, cls = tid & 1;
        float s = bfc[cls];
        for (int k = 0; k < 64; ++k) s += hfin[b * 64 + k] * Wfc[cls * 64 + k];
        out[(size_t)(bb + b) * 2 + cls] = s;
    }
}

extern "C" void kernel_launch(void* const* d_in, const int* in_sizes, int n_in,
                              void* d_out, int out_size, void* d_ws, size_t ws_size,
                              hipStream_t stream) {
    const float* x    = (const float*)d_in[0];
    const float* Wih0 = (const float*)d_in[1];
    const float* Whh0 = (const float*)d_in[2];
    const float* bih0 = (const float*)d_in[3];
    const float* bhh0 = (const float*)d_in[4];
    const float* Wih1 = (const float*)d_in[5];
    const float* Whh1 = (const float*)d_in[6];
    const float* bih1 = (const float*)d_in[7];
    const float* bhh1 = (const float*)d_in[8];
    const float* Wfc  = (const float*)d_in[9];
    const float* bfc  = (const float*)d_in[10];
    float* out = (float*)d_out;

    lstm2_kernel<<<NBLK, 128, 0, stream>>>(x, Wih0, Whh0, bih0, bhh0,
                                           Wih1, Whh1, bih1, bhh1, Wfc, bfc, out);
}

// Round 13
// 260.169 us; speedup vs baseline: 1.3496x; 1.3496x over previous
//
#include <hip/hip_runtime.h>
#include <hip/hip_bf16.h>

#define BATCH 4096
#define TSTEPS 256
#define NF 5
#define H 64
#define BT 8           // batch tile per block (sparse rows 0,1,4,5,8,9,12,13)
#define LDH 136        // hreg row stride in ushorts
#define NBLK (BATCH / BT)   // 512 blocks -> 2 blocks/CU -> 2 waves/SIMD

typedef __attribute__((ext_vector_type(8))) short bf16x8;
typedef __attribute__((ext_vector_type(4))) float f32x4;

#define LOG2E 1.4426950408889634f
#define TWOLOG2E 2.8853900817779268f

__device__ __forceinline__ ushort f2bf(float f) {
    union { float f; unsigned u; } v; v.f = f;
    unsigned u = v.u;
    unsigned r = (u + 0x7FFFu + ((u >> 16) & 1u)) >> 16;  // RNE
    return (ushort)r;
}
__device__ __forceinline__ float bf2f(ushort s) {
    union { unsigned u; float f; } v; v.u = ((unsigned)s) << 16;
    return v.f;
}
__device__ __forceinline__ unsigned pk_bf16(float lo, float hi) {
    unsigned pk;
    asm("v_cvt_pk_bf16_f32 %0, %1, %2" : "=v"(pk) : "v"(lo), "v"(hi));
    return pk;
}

__global__ __launch_bounds__(256, 2)
void lstm2_kernel(const float* __restrict__ x,
                  const float* __restrict__ Wih0, const float* __restrict__ Whh0,
                  const float* __restrict__ bih0, const float* __restrict__ bhh0,
                  const float* __restrict__ Wih1, const float* __restrict__ Whh1,
                  const float* __restrict__ bih1, const float* __restrict__ bhh1,
                  const float* __restrict__ Wfc, const float* __restrict__ bfc,
                  float* __restrict__ out)
{
    __shared__ union {
        ushort xs[TSTEPS * BT * 8];   // bf16 x [t][b][8]; cols 5,6 = 1.0 (bias), 7 = 0
        float  hfin[BT * H];          // epilogue: fp32 final h1
    } uS;
    __shared__ ushort hreg[2][16 * LDH];  // dbuf state; cols 0..63 h0, 64..127 h1

    const int tid = threadIdx.x;
    const int w   = tid >> 6;
    const int l   = tid & 63;
    const int g   = l >> 4;
    const int lr  = l & 15;
    const int bb  = blockIdx.x * BT;

    // ---- stage x tile into LDS as bf16; pad cols 5,6 = 1.0 (bias cols) ----
    {
        const int b  = tid & 7;
        const int t0 = tid >> 3;
        const ushort one = f2bf(1.0f);
        for (int tt = t0; tt < TSTEPS; tt += 32) {
            const float* xp = x + ((size_t)(bb + b) * TSTEPS + tt) * NF;
            bf16x8 v;
            v[0] = (short)f2bf(xp[0]); v[1] = (short)f2bf(xp[1]);
            v[2] = (short)f2bf(xp[2]); v[3] = (short)f2bf(xp[3]);
            v[4] = (short)f2bf(xp[4]); v[5] = (short)one; v[6] = (short)one; v[7] = 0;
            *(bf16x8*)&uS.xs[(tt * BT + b) * 8] = v;
        }
    }
    for (int i = tid; i < 2 * 16 * LDH; i += 256) (&hreg[0][0])[i] = 0;

    // ---- weight fragments resident in VGPRs, gate-scaled for fused EW ----
    // gates i,f,o scaled +log2e; gate g scaled +2log2e.
    // wave w covers unit u = 16w+lr; gate gi at col n = 64*gi + u.
    // k-map (A and B): chunk c, group g, elem j -> k = 32c + 8g + j.
    const int u = 16 * w + lr;
    bf16x8 w0f[4][3], w1f[4][4];
    f32x4 b1acc[4];
    #pragma unroll
    for (int gi = 0; gi < 4; ++gi) {
        const float sc = (gi == 2) ? TWOLOG2E : LOG2E;
        const int n = 64 * gi + u;
        const float b0 = (bih0[n] + bhh0[n]) * sc;
        const float b1 = (bih1[n] + bhh1[n]) * sc;
        { f32x4 a = {b1, b1, b1, b1}; b1acc[gi] = a; }
        #pragma unroll
        for (int c = 0; c < 2; ++c) {
            const float* p = Whh0 + n * H + 32 * c + 8 * g;
            bf16x8 v;
            #pragma unroll
            for (int j = 0; j < 8; ++j) v[j] = (short)f2bf(p[j] * sc);
            w0f[gi][c] = v;
        }
        {
            const ushort bhi = f2bf(b0);
            const ushort blo = f2bf(b0 - bf2f(bhi));
            bf16x8 v;
            #pragma unroll
            for (int j = 0; j < 8; ++j) {
                int kk = 8 * g + j;
                ushort val = 0;
                if (kk < NF) val = f2bf(Wih0[n * NF + kk] * sc);
                else if (kk == 5) val = bhi;
                else if (kk == 6) val = blo;
                v[j] = (short)val;
            }
            w0f[gi][2] = v;
        }
        #pragma unroll
        for (int c = 0; c < 4; ++c) {
            const float* p = (c < 2) ? (Wih1 + n * H + 32 * c + 8 * g)
                                     : (Whh1 + n * H + 32 * (c - 2) + 8 * g);
            bf16x8 v;
            #pragma unroll
            for (int j = 0; j < 8; ++j) v[j] = (short)f2bf(p[j] * sc);
            w1f[gi][c] = v;
        }
    }

    // fused LSTM cell: 5 exp2 + 2 rcp.
    auto cellfuse = [&](float xi, float xf, float xg, float xo, float& cst) -> float {
        float ei = __builtin_amdgcn_exp2f(xi);
        float ef = __builtin_amdgcn_exp2f(xf);
        float Eg = __builtin_amdgcn_exp2f(xg);
        float eo = __builtin_amdgcn_exp2f(xo);
        float a1 = ei + 1.0f, a2 = ef + 1.0f, a3 = Eg + 1.0f, a4 = Eg - 1.0f;
        float P  = a1 * a3;
        float t1 = ef * cst;
        float t3 = (a2 * ei) * a4;
        float num = fmaf(t1, P, t3);
        float R  = __builtin_amdgcn_rcpf(P * a2);
        float cn = num * R;
        cst = cn;
        float ct = __builtin_amdgcn_fmed3f(cn * TWOLOG2E, -15.0f, 15.0f);
        float Ec = __builtin_amdgcn_exp2f(ct);
        return (eo * (Ec - 1.0f)) * __builtin_amdgcn_rcpf((eo + 1.0f) * (Ec + 1.0f));
    };

    float c0[2] = {0, 0}, c1[2] = {0, 0};
    float h1fin[2] = {0, 0};
    const bool xlane = (g == 0) && ((lr & 2) == 0);
    const int  bx    = ((lr >> 2) << 1) | (lr & 1);

    __syncthreads();

    const int arow = lr * LDH;
    const f32x4 kZ = {0, 0, 0, 0};
    const bf16x8 kZ8 = {0, 0, 0, 0, 0, 0, 0, 0};

    // hazard-free x prefetch (xs is read-only during the loop)
    auto load_ax = [&](int t) -> bf16x8 {
        int tc = t < TSTEPS ? t : TSTEPS - 1;
        bf16x8 v = *(const bf16x8*)&uS.xs[(tc * BT + bx) * 8];
        return xlane ? v : kZ8;
    };

    // Pipelined: step t = layer0(t) [h0(t-1), x(t)] + layer1(t-1).
    // 1 barrier/step; ax passed in pre-loaded (off the post-barrier read burst).
    auto body = [&](int t, const ushort* __restrict__ rb, ushort* __restrict__ wb,
                    bf16x8 ax) {
        const bool do0 = (t < TSTEPS);
        const bool do1 = (t >= 1);

        bf16x8 a00 = *(const bf16x8*)&rb[arow + 8 * g];
        bf16x8 a01 = *(const bf16x8*)&rb[arow + 32 + 8 * g];
        bf16x8 a12, a13;
        if (do1) {
            a12 = *(const bf16x8*)&rb[arow + 64 + 8 * g];
            a13 = *(const bf16x8*)&rb[arow + 96 + 8 * g];
        }

        f32x4 acc0[4], accC[4], accD[4];
        __builtin_amdgcn_s_setprio(1);
        if (do0) {
            #pragma unroll
            for (int gi = 0; gi < 4; ++gi) acc0[gi] = __builtin_amdgcn_mfma_f32_16x16x32_bf16(a00, w0f[gi][0], kZ, 0, 0, 0);
            #pragma unroll
            for (int gi = 0; gi < 4; ++gi) acc0[gi] = __builtin_amdgcn_mfma_f32_16x16x32_bf16(a01, w0f[gi][1], acc0[gi], 0, 0, 0);
            #pragma unroll
            for (int gi = 0; gi < 4; ++gi) acc0[gi] = __builtin_amdgcn_mfma_f32_16x16x32_bf16(ax,  w0f[gi][2], acc0[gi], 0, 0, 0);
        }
        if (do1) {
            // L1 as two independent 2-chains (halved dependent-MFMA depth)
            #pragma unroll
            for (int gi = 0; gi < 4; ++gi) accC[gi] = __builtin_amdgcn_mfma_f32_16x16x32_bf16(a00, w1f[gi][0], b1acc[gi], 0, 0, 0);
            #pragma unroll
            for (int gi = 0; gi < 4; ++gi) accD[gi] = __builtin_amdgcn_mfma_f32_16x16x32_bf16(a12, w1f[gi][2], kZ, 0, 0, 0);
            #pragma unroll
            for (int gi = 0; gi < 4; ++gi) accC[gi] = __builtin_amdgcn_mfma_f32_16x16x32_bf16(a01, w1f[gi][1], accC[gi], 0, 0, 0);
            #pragma unroll
            for (int gi = 0; gi < 4; ++gi) accD[gi] = __builtin_amdgcn_mfma_f32_16x16x32_bf16(a13, w1f[gi][3], accD[gi], 0, 0, 0);
        }
        __builtin_amdgcn_s_setprio(0);

        if (do0) {
            float hh[2];
            #pragma unroll
            for (int r = 0; r < 2; ++r)
                hh[r] = cellfuse(acc0[0][r], acc0[1][r], acc0[2][r], acc0[3][r], c0[r]);
            unsigned pk = pk_bf16(hh[0], hh[1]);
            wb[(4 * g + 0) * LDH + u] = (ushort)pk;
            wb[(4 * g + 1) * LDH + u] = (ushort)(pk >> 16);
        }
        if (do1) {
            float hh[2];
            #pragma unroll
            for (int r = 0; r < 2; ++r) {
                hh[r] = cellfuse(accC[0][r] + accD[0][r], accC[1][r] + accD[1][r],
                                 accC[2][r] + accD[2][r], accC[3][r] + accD[3][r], c1[r]);
                h1fin[r] = hh[r];
            }
            unsigned pk = pk_bf16(hh[0], hh[1]);
            wb[(4 * g + 0) * LDH + 64 + u] = (ushort)pk;
            wb[(4 * g + 1) * LDH + 64 + u] = (ushort)(pk >> 16);
        }
        __syncthreads();
    };

    bf16x8 axA = load_ax(0);
    bf16x8 axB = load_ax(1);
    #pragma unroll 1
    for (int t = 0; t < TSTEPS; t += 2) {
        body(t, hreg[0], hreg[1], axA);
        axA = load_ax(t + 2);
        body(t + 1, hreg[1], hreg[0], axB);
        axB = load_ax(t + 3);
    }
    body(TSTEPS, hreg[0], hreg[1], kZ8);   // drain: layer1 step T-1

    // epilogue: FC on fp32 final h1
    #pragma unroll
    for (int r = 0; r < 2; ++r) uS.hfin[(2 * g + r) * H + u] = h1fin[r];
    __syncthreads();
    if (tid < BT * 2) {
        const int b = tid >> 1, cls = tid & 1;
        float s = bfc[cls];
        for (int k = 0; k < H; ++k) s += uS.hfin[b * H + k] * Wfc[cls * H + k];
        out[(size_t)(bb + b) * 2 + cls] = s;
    }
}

extern "C" void kernel_launch(void* const* d_in, const int* in_sizes, int n_in,
                              void* d_out, int out_size, void* d_ws, size_t ws_size,
                              hipStream_t stream) {
    const float* x    = (const float*)d_in[0];
    const float* Wih0 = (const float*)d_in[1];
    const float* Whh0 = (const float*)d_in[2];
    const float* bih0 = (const float*)d_in[3];
    const float* bhh0 = (const float*)d_in[4];
    const float* Wih1 = (const float*)d_in[5];
    const float* Whh1 = (const float*)d_in[6];
    const float* bih1 = (const float*)d_in[7];
    const float* bhh1 = (const float*)d_in[8];
    const float* Wfc  = (const float*)d_in[9];
    const float* bfc  = (const float*)d_in[10];
    float* out = (float*)d_out;

    lstm2_kernel<<<NBLK, 256, 0, stream>>>(x, Wih0, Whh0, bih0, bhh0,
                                           Wih1, Whh1, bih1, bhh1, Wfc, bfc, out);
}

// Round 14
// 257.490 us; speedup vs baseline: 1.3637x; 1.0104x over previous
//
#include <hip/hip_runtime.h>
#include <hip/hip_bf16.h>

#define BATCH 4096
#define TSTEPS 256
#define NF 5
#define H 64
#define BT 8           // batch tile per block (sparse rows 0,1,4,5,8,9,12,13)
#define LDH 136        // hreg row stride in ushorts
#define NBLK (BATCH / BT)   // 512 blocks -> 2 blocks/CU -> 2 waves/SIMD

typedef __attribute__((ext_vector_type(8))) short bf16x8;
typedef __attribute__((ext_vector_type(4))) float f32x4;

#define LOG2E 1.4426950408889634f
#define TWOLOG2E 2.8853900817779268f

__device__ __forceinline__ ushort f2bf(float f) {
    union { float f; unsigned u; } v; v.f = f;
    unsigned u = v.u;
    unsigned r = (u + 0x7FFFu + ((u >> 16) & 1u)) >> 16;  // RNE
    return (ushort)r;
}
__device__ __forceinline__ float bf2f(ushort s) {
    union { unsigned u; float f; } v; v.u = ((unsigned)s) << 16;
    return v.f;
}
__device__ __forceinline__ unsigned pk_bf16(float lo, float hi) {
    unsigned pk;
    asm("v_cvt_pk_bf16_f32 %0, %1, %2" : "=v"(pk) : "v"(lo), "v"(hi));
    return pk;
}

__global__ __launch_bounds__(256, 2)
void lstm2_kernel(const float* __restrict__ x,
                  const float* __restrict__ Wih0, const float* __restrict__ Whh0,
                  const float* __restrict__ bih0, const float* __restrict__ bhh0,
                  const float* __restrict__ Wih1, const float* __restrict__ Whh1,
                  const float* __restrict__ bih1, const float* __restrict__ bhh1,
                  const float* __restrict__ Wfc, const float* __restrict__ bfc,
                  float* __restrict__ out)
{
    __shared__ union {
        ushort xs[TSTEPS * BT * 8];   // bf16 x [t][b][8]; cols 5,6 = 1.0 (bias), 7 = 0
        float  hfin[BT * H];          // epilogue: fp32 final h1
    } uS;
    __shared__ ushort hreg[2][16 * LDH];  // dbuf state; cols 0..63 h0, 64..127 h1

    const int tid = threadIdx.x;
    const int w   = tid >> 6;
    const int l   = tid & 63;
    const int g   = l >> 4;
    const int lr  = l & 15;
    const int bb  = blockIdx.x * BT;

    // ---- stage x tile into LDS as bf16; pad cols 5,6 = 1.0 (bias cols) ----
    {
        const int b  = tid & 7;
        const int t0 = tid >> 3;
        const ushort one = f2bf(1.0f);
        for (int tt = t0; tt < TSTEPS; tt += 32) {
            const float* xp = x + ((size_t)(bb + b) * TSTEPS + tt) * NF;
            bf16x8 v;
            v[0] = (short)f2bf(xp[0]); v[1] = (short)f2bf(xp[1]);
            v[2] = (short)f2bf(xp[2]); v[3] = (short)f2bf(xp[3]);
            v[4] = (short)f2bf(xp[4]); v[5] = (short)one; v[6] = (short)one; v[7] = 0;
            *(bf16x8*)&uS.xs[(tt * BT + b) * 8] = v;
        }
    }
    for (int i = tid; i < 2 * 16 * LDH; i += 256) (&hreg[0][0])[i] = 0;

    // ---- weight fragments resident in VGPRs, gate-scaled for fused EW ----
    // gates i,f,o scaled +log2e; gate g scaled +2log2e.
    // wave w covers unit u = 16w+lr; gate gi at col n = 64*gi + u.
    // k-map (A and B): chunk c, group g, elem j -> k = 32c + 8g + j.
    const int u = 16 * w + lr;
    bf16x8 w0f[4][3], w1f[4][4];
    f32x4 b1acc[4];
    #pragma unroll
    for (int gi = 0; gi < 4; ++gi) {
        const float sc = (gi == 2) ? TWOLOG2E : LOG2E;
        const int n = 64 * gi + u;
        const float b0 = (bih0[n] + bhh0[n]) * sc;
        const float b1 = (bih1[n] + bhh1[n]) * sc;
        { f32x4 a = {b1, b1, b1, b1}; b1acc[gi] = a; }
        #pragma unroll
        for (int c = 0; c < 2; ++c) {
            const float* p = Whh0 + n * H + 32 * c + 8 * g;
            bf16x8 v;
            #pragma unroll
            for (int j = 0; j < 8; ++j) v[j] = (short)f2bf(p[j] * sc);
            w0f[gi][c] = v;
        }
        {
            const ushort bhi = f2bf(b0);
            const ushort blo = f2bf(b0 - bf2f(bhi));
            bf16x8 v;
            #pragma unroll
            for (int j = 0; j < 8; ++j) {
                int kk = 8 * g + j;
                ushort val = 0;
                if (kk < NF) val = f2bf(Wih0[n * NF + kk] * sc);
                else if (kk == 5) val = bhi;
                else if (kk == 6) val = blo;
                v[j] = (short)val;
            }
            w0f[gi][2] = v;
        }
        #pragma unroll
        for (int c = 0; c < 4; ++c) {
            const float* p = (c < 2) ? (Wih1 + n * H + 32 * c + 8 * g)
                                     : (Whh1 + n * H + 32 * (c - 2) + 8 * g);
            bf16x8 v;
            #pragma unroll
            for (int j = 0; j < 8; ++j) v[j] = (short)f2bf(p[j] * sc);
            w1f[gi][c] = v;
        }
    }

    // fused LSTM cell: 5 exp2 + 2 rcp.
    auto cellfuse = [&](float xi, float xf, float xg, float xo, float& cst) -> float {
        float ei = __builtin_amdgcn_exp2f(xi);
        float ef = __builtin_amdgcn_exp2f(xf);
        float Eg = __builtin_amdgcn_exp2f(xg);
        float eo = __builtin_amdgcn_exp2f(xo);
        float a1 = ei + 1.0f, a2 = ef + 1.0f, a3 = Eg + 1.0f, a4 = Eg - 1.0f;
        float P  = a1 * a3;
        float t1 = ef * cst;
        float t3 = (a2 * ei) * a4;
        float num = fmaf(t1, P, t3);
        float R  = __builtin_amdgcn_rcpf(P * a2);
        float cn = num * R;
        cst = cn;
        float ct = __builtin_amdgcn_fmed3f(cn * TWOLOG2E, -15.0f, 15.0f);
        float Ec = __builtin_amdgcn_exp2f(ct);
        return (eo * (Ec - 1.0f)) * __builtin_amdgcn_rcpf((eo + 1.0f) * (Ec + 1.0f));
    };

    float c0[2] = {0, 0}, c1[2] = {0, 0};
    float h1fin[2] = {0, 0};
    const bool xlane = (g == 0) && ((lr & 2) == 0);
    const int  bx    = ((lr >> 2) << 1) | (lr & 1);

    __syncthreads();

    const int arow = lr * LDH;
    const f32x4 kZ = {0, 0, 0, 0};
    const bf16x8 kZ8 = {0, 0, 0, 0, 0, 0, 0, 0};

    // hazard-free x prefetch (xs is read-only during the loop)
    auto load_ax = [&](int t) -> bf16x8 {
        int tc = t < TSTEPS ? t : TSTEPS - 1;
        bf16x8 v = *(const bf16x8*)&uS.xs[(tc * BT + bx) * 8];
        return xlane ? v : kZ8;
    };

    // Pipelined: step t = layer0(t) [h0(t-1), x(t)] + layer1(t-1).
    // R7's exact no-spill body (2 chained acc sets) + prefetched ax + setprio.
    auto body = [&](int t, const ushort* __restrict__ rb, ushort* __restrict__ wb,
                    bf16x8 ax) {
        const bool do0 = (t < TSTEPS);
        const bool do1 = (t >= 1);

        bf16x8 a00 = *(const bf16x8*)&rb[arow + 8 * g];
        bf16x8 a01 = *(const bf16x8*)&rb[arow + 32 + 8 * g];
        bf16x8 a12, a13;
        if (do1) {
            a12 = *(const bf16x8*)&rb[arow + 64 + 8 * g];
            a13 = *(const bf16x8*)&rb[arow + 96 + 8 * g];
        }

        f32x4 acc0[4], acc1[4];
        __builtin_amdgcn_s_setprio(1);
        if (do0) {
            #pragma unroll
            for (int gi = 0; gi < 4; ++gi) acc0[gi] = __builtin_amdgcn_mfma_f32_16x16x32_bf16(a00, w0f[gi][0], kZ, 0, 0, 0);
            #pragma unroll
            for (int gi = 0; gi < 4; ++gi) acc0[gi] = __builtin_amdgcn_mfma_f32_16x16x32_bf16(a01, w0f[gi][1], acc0[gi], 0, 0, 0);
            #pragma unroll
            for (int gi = 0; gi < 4; ++gi) acc0[gi] = __builtin_amdgcn_mfma_f32_16x16x32_bf16(ax,  w0f[gi][2], acc0[gi], 0, 0, 0);
        }
        if (do1) {
            #pragma unroll
            for (int gi = 0; gi < 4; ++gi) acc1[gi] = __builtin_amdgcn_mfma_f32_16x16x32_bf16(a00, w1f[gi][0], b1acc[gi], 0, 0, 0);
            #pragma unroll
            for (int gi = 0; gi < 4; ++gi) acc1[gi] = __builtin_amdgcn_mfma_f32_16x16x32_bf16(a01, w1f[gi][1], acc1[gi], 0, 0, 0);
            #pragma unroll
            for (int gi = 0; gi < 4; ++gi) acc1[gi] = __builtin_amdgcn_mfma_f32_16x16x32_bf16(a12, w1f[gi][2], acc1[gi], 0, 0, 0);
            #pragma unroll
            for (int gi = 0; gi < 4; ++gi) acc1[gi] = __builtin_amdgcn_mfma_f32_16x16x32_bf16(a13, w1f[gi][3], acc1[gi], 0, 0, 0);
        }
        __builtin_amdgcn_s_setprio(0);

        if (do0) {
            float hh[2];
            #pragma unroll
            for (int r = 0; r < 2; ++r)
                hh[r] = cellfuse(acc0[0][r], acc0[1][r], acc0[2][r], acc0[3][r], c0[r]);
            unsigned pk = pk_bf16(hh[0], hh[1]);
            wb[(4 * g + 0) * LDH + u] = (ushort)pk;
            wb[(4 * g + 1) * LDH + u] = (ushort)(pk >> 16);
        }
        if (do1) {
            float hh[2];
            #pragma unroll
            for (int r = 0; r < 2; ++r) {
                hh[r] = cellfuse(acc1[0][r], acc1[1][r], acc1[2][r], acc1[3][r], c1[r]);
                h1fin[r] = hh[r];
            }
            unsigned pk = pk_bf16(hh[0], hh[1]);
            wb[(4 * g + 0) * LDH + 64 + u] = (ushort)pk;
            wb[(4 * g + 1) * LDH + 64 + u] = (ushort)(pk >> 16);
        }
        __syncthreads();
    };

    bf16x8 axA = load_ax(0);
    bf16x8 axB = load_ax(1);
    #pragma unroll 1
    for (int t = 0; t < TSTEPS; t += 2) {
        body(t, hreg[0], hreg[1], axA);
        axA = load_ax(t + 2);
        body(t + 1, hreg[1], hreg[0], axB);
        axB = load_ax(t + 3);
    }
    body(TSTEPS, hreg[0], hreg[1], kZ8);   // drain: layer1 step T-1

    // epilogue: FC on fp32 final h1
    #pragma unroll
    for (int r = 0; r < 2; ++r) uS.hfin[(2 * g + r) * H + u] = h1fin[r];
    __syncthreads();
    if (tid < BT * 2) {
        const int b = tid >> 1, cls = tid & 1;
        float s = bfc[cls];
        for (int k = 0; k < H; ++k) s += uS.hfin[b * H + k] * Wfc[cls * H + k];
        out[(size_t)(bb + b) * 2 + cls] = s;
    }
}

extern "C" void kernel_launch(void* const* d_in, const int* in_sizes, int n_in,
                              void* d_out, int out_size, void* d_ws, size_t ws_size,
                              hipStream_t stream) {
    const float* x    = (const float*)d_in[0];
    const float* Wih0 = (const float*)d_in[1];
    const float* Whh0 = (const float*)d_in[2];
    const float* bih0 = (const float*)d_in[3];
    const float* bhh0 = (const float*)d_in[4];
    const float* Wih1 = (const float*)d_in[5];
    const float* Whh1 = (const float*)d_in[6];
    const float* bih1 = (const float*)d_in[7];
    const float* bhh1 = (const float*)d_in[8];
    const float* Wfc  = (const float*)d_in[9];
    const float* bfc  = (const float*)d_in[10];
    float* out = (float*)d_out;

    lstm2_kernel<<<NBLK, 256, 0, stream>>>(x, Wih0, Whh0, bih0, bhh0,
                                           Wih1, Whh1, bih1, bhh1, Wfc, bfc, out);
}